// Round 6
// baseline (111.485 us; speedup 1.0000x reference)
//
#include <hip/hip_runtime.h>
#include <math.h>

#define EPSF 1e-7f
#define BETA_F 0.08838834764831845f

typedef __attribute__((ext_vector_type(8))) short bf8_t;   // 8 x bf16 bits
typedef __attribute__((ext_vector_type(4))) float f32x4;

// ---------------- workspace layout (float offsets) ----------------
// Qs fp32 = 131072 f; Q bf16 plane = 1024*128us = 65536 f; K/V plane = 2048*128us = 131072 f
#define WS_QT    0          // 1024
#define WS_LQ    1024       // 1024
#define WS_KT    2048       // 2048
#define WS_VT    4096       // 2048
#define WS_LV    6144       // 2048
#define WS_QS    8192       // 131072 -> [8192,139264)
#define WS_QHI   139264     // 65536  -> [139264,204800)
#define WS_QLO   204800     // 65536  -> [204800,270336)
#define WS_KHI   270336     // 131072 -> [270336,401408)
#define WS_KLO   401408     // [401408,532480)
#define WS_VHI   532480     // [532480,663552)
#define WS_VLO   663552     // [663552,794624)
#define WS_VTHI  794624     // [794624,925696)
#define WS_VTLO  925696     // [925696,1056768)
#define WS_PART  1056768    // 1024*8*132 = 1081344 -> total 2138112 f = 8.55 MB (R3-proven)
// Transients aliased into PART (all dead before attn_mfma writes part):
// WKT planes 3x32768, WVT planes 3x8192, V1 planes 3x131072 -> ends at PART+516096 < 1081344

__device__ __forceinline__ float wave_sum(float v) {
#pragma unroll
  for (int off = 32; off > 0; off >>= 1) v += __shfl_xor(v, off);
  return v;
}
__device__ __forceinline__ unsigned short f2bf(float x) {
  unsigned int u = __float_as_uint(x);
  u += 0x7FFFu + ((u >> 16) & 1u);
  return (unsigned short)(u >> 16);
}
__device__ __forceinline__ float bf2f(unsigned short h) {
  return __uint_as_float(((unsigned int)h) << 16);
}
__device__ __forceinline__ void split3(float x, unsigned short& s0, unsigned short& s1,
                                       unsigned short& s2) {
  s0 = f2bf(x);
  float r1 = x - bf2f(s0);
  s1 = f2bf(r1);
  s2 = f2bf(r1 - bf2f(s1));
}
__device__ __forceinline__ bf8_t ld8(const unsigned short* p) {
  return __builtin_bit_cast(bf8_t, *(const uint4*)p);
}
__device__ __forceinline__ f32x4 mfma16(bf8_t a, bf8_t b, f32x4 c) {
  return __builtin_amdgcn_mfma_f32_16x16x32_bf16(a, b, c, 0, 0, 0);
}

// ---------------- prep Q ----------------
__global__ void prep_q(const float* __restrict__ queries, float* __restrict__ Qs,
                       float* __restrict__ qt, float* __restrict__ lqv,
                       unsigned int* __restrict__ Qhi, unsigned int* __restrict__ Qlo) {
  int i = blockIdx.x;
  int lane = threadIdx.x;  // 64
  float2 r = ((const float2*)(queries + (size_t)i * 128))[lane];
  float s2 = wave_sum(r.x * r.x + r.y * r.y);
  float n = sqrtf(s2);
  float f = fminf(3.5f / (n + EPSF), 1.0f);
  float t = fmaxf(n * f, EPSF);
  float coef = sinhf(t) / t * f;
  float ch = coshf(t);
  float x0 = coef * r.x, x1 = coef * r.y;
  ((float2*)(Qs + (size_t)i * 128))[lane] = make_float2(x0, x1);
  unsigned short h0 = f2bf(x0), h1 = f2bf(x1);
  Qhi[i * 64 + lane] = (unsigned)h0 | ((unsigned)h1 << 16);
  unsigned short g0 = f2bf(x0 - bf2f(h0)), g1 = f2bf(x1 - bf2f(h1));
  Qlo[i * 64 + lane] = (unsigned)g0 | ((unsigned)g1 << 16);
  if (lane == 0) {
    qt[i] = ch;
    lqv[i] = coef * coef * s2 - ch * ch;
  }
}

// ---------------- convert + transpose weights to 3-plane bf16 ----------------
__global__ void convert_w(const float* __restrict__ WK, const float* __restrict__ WV,
                          unsigned short* __restrict__ WKT0, unsigned short* __restrict__ WKT1,
                          unsigned short* __restrict__ WKT2,
                          unsigned short* __restrict__ WVT0, unsigned short* __restrict__ WVT1,
                          unsigned short* __restrict__ WVT2) {
  int t = blockIdx.x * 256 + threadIdx.x;
  if (t < 65536) {                       // W_K: 512x128 -> WKT[128][512]
    int n = t >> 9, k = t & 511;
    unsigned short a, b, c;
    split3(WK[k * 128 + n], a, b, c);
    WKT0[t] = a; WKT1[t] = b; WKT2[t] = c;
  } else {                               // W_V: 128x128 -> WVT[128][128]
    int t2 = t - 65536;
    int n = t2 >> 7, k = t2 & 127;
    unsigned short a, b, c;
    split3(WV[k * 128 + n], a, b, c);
    WVT0[t2] = a; WVT1[t2] = b; WVT2[t2] = c;
  }
}

// ---------------- fused K / V1 GEMM (MFMA, 3-way split, 6-pass) ----------------
// blocks 0..127: K = tangent(keys @ W_K)  -> Khi/Klo + kt
// blocks 128..255: V1 = values @ W_K      -> V1 planes (raw)
__launch_bounds__(64)
__global__ void gemm_kv1(const float* __restrict__ keys, const float* __restrict__ values,
                         const unsigned short* __restrict__ WKT0,
                         const unsigned short* __restrict__ WKT1,
                         const unsigned short* __restrict__ WKT2,
                         unsigned short* __restrict__ Khi, unsigned short* __restrict__ Klo,
                         float* __restrict__ kt,
                         unsigned short* __restrict__ V10, unsigned short* __restrict__ V11,
                         unsigned short* __restrict__ V12) {
  int b = blockIdx.x;
  bool isK = b < 128;
  int r0 = (b & 127) * 16;
  const float* src = isK ? keys : values;
  int lane = threadIdx.x, l15 = lane & 15, lh = lane >> 4;

  f32x4 acc[8];
#pragma unroll
  for (int n = 0; n < 8; ++n) acc[n] = f32x4{0, 0, 0, 0};

  const float* arow = src + (size_t)(r0 + l15) * 512 + lh * 8;
#pragma unroll 2
  for (int ks = 0; ks < 16; ++ks) {
    float4 a0 = *(const float4*)(arow + ks * 32);
    float4 a1 = *(const float4*)(arow + ks * 32 + 4);
    float av[8] = {a0.x, a0.y, a0.z, a0.w, a1.x, a1.y, a1.z, a1.w};
    bf8_t aa0, aa1, aa2;
#pragma unroll
    for (int i = 0; i < 8; ++i) {
      unsigned short p0, p1, p2;
      split3(av[i], p0, p1, p2);
      aa0[i] = (short)p0; aa1[i] = (short)p1; aa2[i] = (short)p2;
    }
#pragma unroll
    for (int n = 0; n < 8; ++n) {
      size_t boff = (size_t)(n * 16 + l15) * 512 + ks * 32 + lh * 8;
      bf8_t b0 = ld8(WKT0 + boff);
      bf8_t b1 = ld8(WKT1 + boff);
      bf8_t b2 = ld8(WKT2 + boff);
      acc[n] = mfma16(aa0, b0, acc[n]);
      acc[n] = mfma16(aa0, b1, acc[n]);
      acc[n] = mfma16(aa1, b0, acc[n]);
      acc[n] = mfma16(aa0, b2, acc[n]);
      acc[n] = mfma16(aa1, b1, acc[n]);
      acc[n] = mfma16(aa2, b0, acc[n]);
    }
  }

  if (isK) {
#pragma unroll
    for (int r = 0; r < 4; ++r) {
      float s2 = 0.f;
#pragma unroll
      for (int n = 0; n < 8; ++n) s2 += acc[n][r] * acc[n][r];
#pragma unroll
      for (int off = 1; off < 16; off <<= 1) s2 += __shfl_xor(s2, off);
      float nn = sqrtf(s2);
      float f = fminf(3.5f / (nn + EPSF), 1.0f);
      float t = fmaxf(nn * f, EPSF);
      float coef = sinhf(t) / t * f;
      int row = r0 + lh * 4 + r;
      if (l15 == 0) kt[row] = coshf(t);
#pragma unroll
      for (int n = 0; n < 8; ++n) {
        float sv = coef * acc[n][r];
        unsigned short h = f2bf(sv);
        Khi[(size_t)row * 128 + n * 16 + l15] = h;
        Klo[(size_t)row * 128 + n * 16 + l15] = f2bf(sv - bf2f(h));
      }
    }
  } else {
#pragma unroll
    for (int r = 0; r < 4; ++r) {
      int row = r0 + lh * 4 + r;
#pragma unroll
      for (int n = 0; n < 8; ++n) {
        unsigned short p0, p1, p2;
        split3(acc[n][r], p0, p1, p2);
        size_t o = (size_t)row * 128 + n * 16 + l15;
        V10[o] = p0; V11[o] = p1; V12[o] = p2;
      }
    }
  }
}

// ---------------- V2 = tangent(V1 @ W_V): 3-way x 3-way, 6-pass ----------------
__launch_bounds__(64)
__global__ void gemm_v2(const unsigned short* __restrict__ V10,
                        const unsigned short* __restrict__ V11,
                        const unsigned short* __restrict__ V12,
                        const unsigned short* __restrict__ WVT0,
                        const unsigned short* __restrict__ WVT1,
                        const unsigned short* __restrict__ WVT2,
                        unsigned short* __restrict__ Vhi, unsigned short* __restrict__ Vlo,
                        unsigned short* __restrict__ VThi, unsigned short* __restrict__ VTlo,
                        float* __restrict__ vt, float* __restrict__ lv) {
  int r0 = blockIdx.x * 16;
  int lane = threadIdx.x, l15 = lane & 15, lh = lane >> 4;
  __shared__ float ldsT[128][17];

  f32x4 acc[8];
#pragma unroll
  for (int n = 0; n < 8; ++n) acc[n] = f32x4{0, 0, 0, 0};

#pragma unroll
  for (int ks = 0; ks < 4; ++ks) {
    size_t aoff = (size_t)(r0 + l15) * 128 + ks * 32 + lh * 8;
    bf8_t a0 = ld8(V10 + aoff);
    bf8_t a1 = ld8(V11 + aoff);
    bf8_t a2 = ld8(V12 + aoff);
#pragma unroll
    for (int n = 0; n < 8; ++n) {
      size_t boff = (size_t)(n * 16 + l15) * 128 + ks * 32 + lh * 8;
      bf8_t b0 = ld8(WVT0 + boff);
      bf8_t b1 = ld8(WVT1 + boff);
      bf8_t b2 = ld8(WVT2 + boff);
      acc[n] = mfma16(a0, b0, acc[n]);
      acc[n] = mfma16(a0, b1, acc[n]);
      acc[n] = mfma16(a1, b0, acc[n]);
      acc[n] = mfma16(a0, b2, acc[n]);
      acc[n] = mfma16(a1, b1, acc[n]);
      acc[n] = mfma16(a2, b0, acc[n]);
    }
  }

#pragma unroll
  for (int r = 0; r < 4; ++r) {
    float s2 = 0.f;
#pragma unroll
    for (int n = 0; n < 8; ++n) s2 += acc[n][r] * acc[n][r];
#pragma unroll
    for (int off = 1; off < 16; off <<= 1) s2 += __shfl_xor(s2, off);
    float nn = sqrtf(s2);
    float f = fminf(3.5f / (nn + EPSF), 1.0f);
    float t = fmaxf(nn * f, EPSF);
    float coef = sinhf(t) / t * f;
    float ch = coshf(t);
    int row = r0 + lh * 4 + r;
    if (l15 == 0) {
      vt[row] = ch;
      lv[row] = coef * coef * s2 - ch * ch;
    }
#pragma unroll
    for (int n = 0; n < 8; ++n) {
      float sv = coef * acc[n][r];
      unsigned short h = f2bf(sv);
      Vhi[(size_t)row * 128 + n * 16 + l15] = h;
      Vlo[(size_t)row * 128 + n * 16 + l15] = f2bf(sv - bf2f(h));
      ldsT[n * 16 + l15][lh * 4 + r] = sv;
    }
  }
  __syncthreads();

  // transposed store: VT[d][r0..r0+15]
#pragma unroll
  for (int e = 0; e < 2; ++e) {
    int d = lane + e * 64;
    unsigned int wh[8], wl[8];
#pragma unroll
    for (int i = 0; i < 8; ++i) {
      float s0 = ldsT[d][2 * i], s1 = ldsT[d][2 * i + 1];
      unsigned short h0 = f2bf(s0), h1 = f2bf(s1);
      unsigned short g0 = f2bf(s0 - bf2f(h0)), g1 = f2bf(s1 - bf2f(h1));
      wh[i] = (unsigned)h0 | ((unsigned)h1 << 16);
      wl[i] = (unsigned)g0 | ((unsigned)g1 << 16);
    }
    size_t o = (size_t)d * 2048 + r0;
    *(uint4*)(VThi + o) = make_uint4(wh[0], wh[1], wh[2], wh[3]);
    *(uint4*)(VThi + o + 8) = make_uint4(wh[4], wh[5], wh[6], wh[7]);
    *(uint4*)(VTlo + o) = make_uint4(wl[0], wl[1], wl[2], wl[3]);
    *(uint4*)(VTlo + o + 8) = make_uint4(wl[4], wl[5], wl[6], wl[7]);
  }
}

// ---------------- MFMA pair phase: 16 q x 64 j per wave, 4 waves merged in-block ----------------
__launch_bounds__(256, 2)
__global__ void attn_mfma(const unsigned short* __restrict__ Qhi, const unsigned short* __restrict__ Qlo,
                          const unsigned short* __restrict__ Khi, const unsigned short* __restrict__ Klo,
                          const unsigned short* __restrict__ Vhi, const unsigned short* __restrict__ Vlo,
                          const unsigned short* __restrict__ VThi, const unsigned short* __restrict__ VTlo,
                          const float* __restrict__ qt, const float* __restrict__ lqv,
                          const float* __restrict__ kt, const float* __restrict__ vt,
                          const float* __restrict__ lv, float* __restrict__ part) {
  int tid = threadIdx.x, wv = tid >> 6, lane = tid & 63;
  int l15 = lane & 15, lh = lane >> 4;
  int qg = blockIdx.x >> 3, sp = blockIdx.x & 7;
  int q0 = qg * 16;
  int j0 = sp * 256 + wv * 64;

  __shared__ __align__(16) unsigned short ghA[4][1024];
  __shared__ __align__(16) unsigned short glA[4][1024];
  __shared__ __align__(16) float mergeO[4][16][132];
  __shared__ float mergeS[4][3][16];

  bf8_t qfh[4], qfl[4];
  {
    const unsigned short* qp = Qhi + (size_t)(q0 + l15) * 128 + lh * 8;
    const unsigned short* ql = Qlo + (size_t)(q0 + l15) * 128 + lh * 8;
#pragma unroll
    for (int ks = 0; ks < 4; ++ks) { qfh[ks] = ld8(qp + ks * 32); qfl[ks] = ld8(ql + ks * 32); }
  }
  float qtr[4], lq2[4];
#pragma unroll
  for (int r = 0; r < 4; ++r) {
    int q = q0 + lh * 4 + r;
    qtr[r] = qt[q];
    lq2[r] = 2.0f + lqv[q];
  }
  float ktj[4], vtj[4], lvj[4];
#pragma unroll
  for (int n = 0; n < 4; ++n) {
    int j = j0 + n * 16 + l15;
    ktj[n] = kt[j]; vtj[n] = vt[j]; lvj[n] = lv[j];
  }

  f32x4 sf[4], cf[4];
#pragma unroll
  for (int n = 0; n < 4; ++n) {
    f32x4 s = {0, 0, 0, 0}, c = {0, 0, 0, 0};
    size_t jrow = (size_t)(j0 + n * 16 + l15) * 128 + lh * 8;
    const unsigned short* kh = Khi + jrow;
    const unsigned short* kl = Klo + jrow;
    const unsigned short* vh = Vhi + jrow;
    const unsigned short* vl = Vlo + jrow;
#pragma unroll
    for (int ks = 0; ks < 4; ++ks) {
      bf8_t bkh = ld8(kh + ks * 32), bkl = ld8(kl + ks * 32);
      s = mfma16(qfh[ks], bkh, s);
      s = mfma16(qfh[ks], bkl, s);
      s = mfma16(qfl[ks], bkh, s);
      bf8_t bvh = ld8(vh + ks * 32), bvl = ld8(vl + ks * 32);
      c = mfma16(qfh[ks], bvh, c);
      c = mfma16(qfh[ks], bvl, c);
      c = mfma16(qfl[ks], bvh, c);
    }
    sf[n] = s; cf[n] = c;
  }

  float lsum[4] = {0, 0, 0, 0}, tcs[4] = {0, 0, 0, 0}, tts[4] = {0, 0, 0, 0};
#pragma unroll
  for (int n = 0; n < 4; ++n) {
#pragma unroll
    for (int r = 0; r < 4; ++r) {
      float sim = sf[n][r] - qtr[r] * ktj[n];
      float c = cf[n][r] - qtr[r] * vtj[n];
      float e = expf(-BETA_F * sim);
      float z = fmaxf(-c, 1.0f + EPSF);
      float dist = acoshf(z);
      float den2 = fmaxf(lvj[n] + lq2[r] * c * c, EPSF);
      float g = e * dist * rsqrtf(den2);
      lsum[r] += e;
      tcs[r] += g * c;
      tts[r] += g * vtj[n];
      unsigned short gh = f2bf(g);
      unsigned short gl = f2bf(g - bf2f(gh));
      int q_ = lh * 4 + r;
      int idx = (q_ * 64 + n * 16 + l15) ^ ((q_ & 7) << 3);
      ghA[wv][idx] = gh;
      glA[wv][idx] = gl;
    }
  }
  asm volatile("s_waitcnt lgkmcnt(0)" ::: "memory");
  __builtin_amdgcn_sched_barrier(0);

  f32x4 accO[8];
#pragma unroll
  for (int dn = 0; dn < 8; ++dn) accO[dn] = f32x4{0, 0, 0, 0};
#pragma unroll
  for (int jk = 0; jk < 2; ++jk) {
    int base = (l15 * 64 + jk * 32 + lh * 8) ^ ((l15 & 7) << 3);
    bf8_t ah = ld8(&ghA[wv][base]);
    bf8_t al = ld8(&glA[wv][base]);
#pragma unroll
    for (int dn = 0; dn < 8; ++dn) {
      size_t vrow = (size_t)(dn * 16 + l15) * 2048 + j0 + jk * 32 + lh * 8;
      bf8_t bh = ld8(VThi + vrow), bl = ld8(VTlo + vrow);
      accO[dn] = mfma16(ah, bh, accO[dn]);
      accO[dn] = mfma16(ah, bl, accO[dn]);
      accO[dn] = mfma16(al, bh, accO[dn]);
    }
  }

#pragma unroll
  for (int r = 0; r < 4; ++r) {
#pragma unroll
    for (int off = 1; off < 16; off <<= 1) {
      lsum[r] += __shfl_xor(lsum[r], off);
      tcs[r] += __shfl_xor(tcs[r], off);
      tts[r] += __shfl_xor(tts[r], off);
    }
  }

#pragma unroll
  for (int r = 0; r < 4; ++r) {
    int q_ = lh * 4 + r;
#pragma unroll
    for (int dn = 0; dn < 8; ++dn) mergeO[wv][q_][dn * 16 + l15] = accO[dn][r];
    if (l15 == 0) {
      mergeS[wv][0][q_] = lsum[r];
      mergeS[wv][1][q_] = tcs[r];
      mergeS[wv][2][q_] = tts[r];
    }
  }
  __syncthreads();

#pragma unroll
  for (int e = 0; e < 2; ++e) {
    int t = tid + e * 256;
    int q_ = t >> 5, d0 = (t & 31) * 4;
    float4 s = make_float4(0.f, 0.f, 0.f, 0.f);
#pragma unroll
    for (int w = 0; w < 4; ++w) {
      float4 v = *(const float4*)&mergeO[w][q_][d0];
      s.x += v.x; s.y += v.y; s.z += v.z; s.w += v.w;
    }
    float* P = part + ((size_t)(q0 + q_) * 8 + sp) * 132;
    *(float4*)(P + d0) = s;
  }
  if (tid < 16) {
    int q_ = tid;
    float a = 0, b = 0, cc2 = 0;
#pragma unroll
    for (int w = 0; w < 4; ++w) {
      a += mergeS[w][0][q_];
      b += mergeS[w][1][q_];
      cc2 += mergeS[w][2][q_];
    }
    float* P = part + ((size_t)(q0 + q_) * 8 + sp) * 132;
    P[128] = a; P[129] = b; P[130] = cc2;
  }
}

// ---------------- merge splits + hyperbolic epilogue ----------------
__global__ void merge_fin(const float* __restrict__ part, const float* __restrict__ Qs,
                          const float* __restrict__ qt, float* __restrict__ out) {
  int qi = blockIdx.x;
  int lane = threadIdx.x;  // 64
  const float* P = part + (size_t)qi * 8 * 132;
  float ox = 0, oy = 0, l = 0, tc = 0, tt = 0;
#pragma unroll
  for (int s = 0; s < 8; ++s) {
    const float* p = P + s * 132;
    float2 o2 = *(const float2*)(p + 2 * lane);
    ox += o2.x; oy += o2.y;
    l += p[128]; tc += p[129]; tt += p[130];
  }
  float2 q2 = ((const float2*)(Qs + (size_t)qi * 128))[lane];
  float qtv = qt[qi];
  float invl = 1.0f / l;
  float Tmx = (ox + tc * q2.x) * invl;
  float Tmy = (oy + tc * q2.y) * invl;
  float Tmt = (tt + tc * qtv) * invl;
  float sp2 = wave_sum(Tmx * Tmx + Tmy * Tmy);
  float LT = sp2 - Tmt * Tmt;
  float un = sqrtf(fmaxf(LT, EPSF));
  float ch = coshf(un);
  float shv = sinhf(un) / un;
  float zx = ch * q2.x + shv * Tmx;
  float zy = ch * q2.y + shv * Tmy;
  float zt = ch * qtv + shv * Tmt;
  float zn2 = wave_sum(zx * zx + zy * zy);
  float nz = fmaxf(sqrtf(zn2), EPSF);
  float dist = acoshf(fmaxf(zt, 1.0f + EPSF));
  float sc = dist / nz;
  ((float2*)(out + (size_t)qi * 128))[lane] = make_float2(sc * zx, sc * zy);
}

extern "C" void kernel_launch(void* const* d_in, const int* in_sizes, int n_in,
                              void* d_out, int out_size, void* d_ws, size_t ws_size,
                              hipStream_t stream) {
  const float* queries = (const float*)d_in[0];
  const float* keys = (const float*)d_in[1];
  const float* values = (const float*)d_in[2];
  const float* WK = (const float*)d_in[3];
  const float* WV = (const float*)d_in[4];
  float* ws = (float*)d_ws;

  float* qt_ = ws + WS_QT;
  float* lq_ = ws + WS_LQ;
  float* kt_ = ws + WS_KT;
  float* vt_ = ws + WS_VT;
  float* lv_ = ws + WS_LV;
  float* Qs = ws + WS_QS;
  unsigned short* Qhi = (unsigned short*)(ws + WS_QHI);
  unsigned short* Qlo = (unsigned short*)(ws + WS_QLO);
  unsigned short* Khi = (unsigned short*)(ws + WS_KHI);
  unsigned short* Klo = (unsigned short*)(ws + WS_KLO);
  unsigned short* Vhi = (unsigned short*)(ws + WS_VHI);
  unsigned short* Vlo = (unsigned short*)(ws + WS_VLO);
  unsigned short* VThi = (unsigned short*)(ws + WS_VTHI);
  unsigned short* VTlo = (unsigned short*)(ws + WS_VTLO);
  float* part = ws + WS_PART;
  // transient aliases inside part (dead before attn_mfma writes part):
  unsigned short* WKT0 = (unsigned short*)(part + 0);
  unsigned short* WKT1 = (unsigned short*)(part + 32768);
  unsigned short* WKT2 = (unsigned short*)(part + 65536);
  unsigned short* WVT0 = (unsigned short*)(part + 98304);
  unsigned short* WVT1 = (unsigned short*)(part + 106496);
  unsigned short* WVT2 = (unsigned short*)(part + 114688);
  unsigned short* V10 = (unsigned short*)(part + 122880);
  unsigned short* V11 = (unsigned short*)(part + 253952);
  unsigned short* V12 = (unsigned short*)(part + 385024);
  float* out = (float*)d_out;

  prep_q<<<1024, 64, 0, stream>>>(queries, Qs, qt_, lq_, (unsigned int*)Qhi, (unsigned int*)Qlo);
  convert_w<<<320, 256, 0, stream>>>(WK, WV, WKT0, WKT1, WKT2, WVT0, WVT1, WVT2);
  gemm_kv1<<<256, 64, 0, stream>>>(keys, values, WKT0, WKT1, WKT2, Khi, Klo, kt_, V10, V11, V12);
  gemm_v2<<<128, 64, 0, stream>>>(V10, V11, V12, WVT0, WVT1, WVT2, Vhi, Vlo, VThi, VTlo, vt_, lv_);
  attn_mfma<<<512, 256, 0, stream>>>(Qhi, Qlo, Khi, Klo, Vhi, Vlo, VThi, VTlo,
                                     qt_, lq_, kt_, vt_, lv_, part);
  merge_fin<<<1024, 64, 0, stream>>>(part, Qs, qt_, out);
}

// Round 9
// 70.113 us; speedup vs baseline: 1.5901x; 1.5901x over previous
//
#include <hip/hip_runtime.h>
#include <math.h>

#define EPSF 1e-7f
#define BETA_F 0.08838834764831845f

typedef __attribute__((ext_vector_type(8))) short bf8_t;   // 8 x bf16 bits
typedef __attribute__((ext_vector_type(4))) float f32x4;

// ---------------- workspace layout (float offsets), all dedicated, no aliasing ----------------
#define WS_QT    0          // 1024
#define WS_LQ    1024       // 1024
#define WS_KT    2048       // 2048
#define WS_VTM   4096       // 2048
#define WS_LV    6144       // 2048
#define WS_QS    8192       // 131072 -> 139264
#define WS_QHI   139264     // 65536
#define WS_QLO   204800     // 65536
#define WS_KHI   270336     // 131072
#define WS_KLO   401408
#define WS_VHI   532480
#define WS_VLO   663552
#define WS_VTHI  794624
#define WS_VTLO  925696
#define WS_WKT0  1056768    // 32768 each
#define WS_WKT1  1089536
#define WS_WKT2  1122304
#define WS_WVT0  1155072    // 8192 each
#define WS_WVT1  1163264
#define WS_WVT2  1171456
#define WS_PART  1179648    // 1081344 -> end 2260992 f = 9.04 MB

__device__ __forceinline__ float wave_sum(float v) {
#pragma unroll
  for (int off = 32; off > 0; off >>= 1) v += __shfl_xor(v, off);
  return v;
}
__device__ __forceinline__ unsigned short f2bf(float x) {
  unsigned int u = __float_as_uint(x);
  u += 0x7FFFu + ((u >> 16) & 1u);
  return (unsigned short)(u >> 16);
}
__device__ __forceinline__ float bf2f(unsigned short h) {
  return __uint_as_float(((unsigned int)h) << 16);
}
__device__ __forceinline__ void split3(float x, unsigned short& s0, unsigned short& s1,
                                       unsigned short& s2) {
  s0 = f2bf(x);
  float r1 = x - bf2f(s0);
  s1 = f2bf(r1);
  s2 = f2bf(r1 - bf2f(s1));
}
__device__ __forceinline__ bf8_t ld8(const unsigned short* p) {
  return __builtin_bit_cast(bf8_t, *(const uint4*)p);
}
__device__ __forceinline__ f32x4 mfma16(bf8_t a, bf8_t b, f32x4 c) {
  return __builtin_amdgcn_mfma_f32_16x16x32_bf16(a, b, c, 0, 0, 0);
}

// ---------------- prep Q (R6 verbatim) ----------------
__global__ void prep_q(const float* __restrict__ queries, float* __restrict__ Qs,
                       float* __restrict__ qt, float* __restrict__ lqv,
                       unsigned int* __restrict__ Qhi, unsigned int* __restrict__ Qlo) {
  int i = blockIdx.x;
  int lane = threadIdx.x;  // 64
  float2 r = ((const float2*)(queries + (size_t)i * 128))[lane];
  float s2 = wave_sum(r.x * r.x + r.y * r.y);
  float n = sqrtf(s2);
  float f = fminf(3.5f / (n + EPSF), 1.0f);
  float t = fmaxf(n * f, EPSF);
  float coef = sinhf(t) / t * f;
  float ch = coshf(t);
  float x0 = coef * r.x, x1 = coef * r.y;
  ((float2*)(Qs + (size_t)i * 128))[lane] = make_float2(x0, x1);
  unsigned short h0 = f2bf(x0), h1 = f2bf(x1);
  Qhi[i * 64 + lane] = (unsigned)h0 | ((unsigned)h1 << 16);
  unsigned short g0 = f2bf(x0 - bf2f(h0)), g1 = f2bf(x1 - bf2f(h1));
  Qlo[i * 64 + lane] = (unsigned)g0 | ((unsigned)g1 << 16);
  if (lane == 0) {
    qt[i] = ch;
    lqv[i] = coef * coef * s2 - ch * ch;
  }
}

// ---------------- convert + transpose weights to 3-plane bf16 (R6 verbatim) ----------------
__global__ void convert_w(const float* __restrict__ WK, const float* __restrict__ WV,
                          unsigned short* __restrict__ WKT0, unsigned short* __restrict__ WKT1,
                          unsigned short* __restrict__ WKT2,
                          unsigned short* __restrict__ WVT0, unsigned short* __restrict__ WVT1,
                          unsigned short* __restrict__ WVT2) {
  int t = blockIdx.x * 256 + threadIdx.x;
  if (t < 65536) {                       // W_K: 512x128 -> WKT[128][512]
    int n = t >> 9, k = t & 511;
    unsigned short a, b, c;
    split3(WK[k * 128 + n], a, b, c);
    WKT0[t] = a; WKT1[t] = b; WKT2[t] = c;
  } else {                               // W_V: 128x128 -> WVT[128][128]
    int t2 = t - 65536;
    int n = t2 >> 7, k = t2 & 127;
    unsigned short a, b, c;
    split3(WV[k * 128 + n], a, b, c);
    WVT0[t2] = a; WVT1[t2] = b; WVT2[t2] = c;
  }
}

// ---------------- fused prep (R6 arithmetic, n-split across 8 waves) ----------------
// 256 blocks x 512 threads. blocks 0..127: K path; 128..255: V path.
// Wave wv computes output-column fragment n = wv. Per-output FP chains identical to R6.
__launch_bounds__(512)
__global__ void prep_kv(const float* __restrict__ keys, const float* __restrict__ values,
                        const unsigned short* __restrict__ WKT0,
                        const unsigned short* __restrict__ WKT1,
                        const unsigned short* __restrict__ WKT2,
                        const unsigned short* __restrict__ WVT0,
                        const unsigned short* __restrict__ WVT1,
                        const unsigned short* __restrict__ WVT2,
                        unsigned short* __restrict__ Khi, unsigned short* __restrict__ Klo,
                        float* __restrict__ kt,
                        unsigned short* __restrict__ Vhi, unsigned short* __restrict__ Vlo,
                        unsigned short* __restrict__ VThi, unsigned short* __restrict__ VTlo,
                        float* __restrict__ vt, float* __restrict__ lv) {
  int tid = threadIdx.x, wv = tid >> 6, lane = tid & 63;
  int l15 = lane & 15, lh = lane >> 4;
  int b = blockIdx.x;
  bool isK = b < 128;
  int r0 = (b & 127) * 16;
  const float* src = isK ? keys : values;

  __shared__ __align__(16) float ldsD[16][132];
  __shared__ __align__(16) unsigned short v1p[3][16][128];
  __shared__ __align__(16) float ldsD2[16][132];
  __shared__ __align__(16) float ldsT[128][17];

  // ---- GEMM1: acc chain identical to R6's acc[n=wv]: ks = 0..15, 6-pass ----
  f32x4 acc = f32x4{0, 0, 0, 0};
  const float* arow = src + (size_t)(r0 + l15) * 512 + lh * 8;
#pragma unroll 2
  for (int ks = 0; ks < 16; ++ks) {
    float4 a0 = *(const float4*)(arow + ks * 32);
    float4 a1 = *(const float4*)(arow + ks * 32 + 4);
    float av[8] = {a0.x, a0.y, a0.z, a0.w, a1.x, a1.y, a1.z, a1.w};
    bf8_t aa0, aa1, aa2;
#pragma unroll
    for (int i = 0; i < 8; ++i) {
      unsigned short p0, p1, p2;
      split3(av[i], p0, p1, p2);
      aa0[i] = (short)p0; aa1[i] = (short)p1; aa2[i] = (short)p2;
    }
    size_t boff = (size_t)(wv * 16 + l15) * 512 + ks * 32 + lh * 8;
    bf8_t b0 = ld8(WKT0 + boff);
    bf8_t b1 = ld8(WKT1 + boff);
    bf8_t b2 = ld8(WKT2 + boff);
    acc = mfma16(aa0, b0, acc);
    acc = mfma16(aa0, b1, acc);
    acc = mfma16(aa1, b0, acc);
    acc = mfma16(aa0, b2, acc);
    acc = mfma16(aa1, b1, acc);
    acc = mfma16(aa2, b0, acc);
  }
#pragma unroll
  for (int r = 0; r < 4; ++r) ldsD[lh * 4 + r][wv * 16 + l15] = acc[r];
  __syncthreads();

  if (isK) {
    // ---- K tangent epilogue (R6 order: sum n=0..7, shfl-xor 1,2,4,8) ----
    if (tid < 256) {
      int row = tid >> 4, l = tid & 15;
      float a[8];
#pragma unroll
      for (int n = 0; n < 8; ++n) a[n] = ldsD[row][n * 16 + l];
      float s2 = 0.f;
#pragma unroll
      for (int n = 0; n < 8; ++n) s2 += a[n] * a[n];
#pragma unroll
      for (int off = 1; off < 16; off <<= 1) s2 += __shfl_xor(s2, off);
      float nn = sqrtf(s2);
      float f = fminf(3.5f / (nn + EPSF), 1.0f);
      float t = fmaxf(nn * f, EPSF);
      float coef = sinhf(t) / t * f;
      if (l == 0) kt[r0 + row] = coshf(t);
#pragma unroll
      for (int n = 0; n < 8; ++n) {
        float sv = coef * a[n];
        unsigned short h = f2bf(sv);
        Khi[(size_t)(r0 + row) * 128 + n * 16 + l] = h;
        Klo[(size_t)(r0 + row) * 128 + n * 16 + l] = f2bf(sv - bf2f(h));
      }
    }
    return;
  }

  // ---- V path: V1 tile -> split3 -> LDS planes (same values R6 round-tripped via global) ----
  if (tid < 256) {
    int row = tid >> 4, l = tid & 15;
#pragma unroll
    for (int n = 0; n < 8; ++n) {
      unsigned short p0, p1, p2;
      split3(ldsD[row][n * 16 + l], p0, p1, p2);
      v1p[0][row][n * 16 + l] = p0;
      v1p[1][row][n * 16 + l] = p1;
      v1p[2][row][n * 16 + l] = p2;
    }
  }
  __syncthreads();

  // ---- GEMM2: acc chain identical to R6 gemm_v2's acc[n=wv]: ks = 0..3, 6-pass ----
  f32x4 a2 = f32x4{0, 0, 0, 0};
#pragma unroll
  for (int ks = 0; ks < 4; ++ks) {
    bf8_t x0 = ld8(&v1p[0][l15][ks * 32 + lh * 8]);
    bf8_t x1 = ld8(&v1p[1][l15][ks * 32 + lh * 8]);
    bf8_t x2 = ld8(&v1p[2][l15][ks * 32 + lh * 8]);
    size_t boff = (size_t)(wv * 16 + l15) * 128 + ks * 32 + lh * 8;
    bf8_t b0 = ld8(WVT0 + boff);
    bf8_t b1 = ld8(WVT1 + boff);
    bf8_t b2 = ld8(WVT2 + boff);
    a2 = mfma16(x0, b0, a2);
    a2 = mfma16(x0, b1, a2);
    a2 = mfma16(x1, b0, a2);
    a2 = mfma16(x0, b2, a2);
    a2 = mfma16(x1, b1, a2);
    a2 = mfma16(x2, b0, a2);
  }
#pragma unroll
  for (int r = 0; r < 4; ++r) ldsD2[lh * 4 + r][wv * 16 + l15] = a2[r];
  __syncthreads();

  // ---- V tangent epilogue (R6 order) ----
  if (tid < 256) {
    int row = tid >> 4, l = tid & 15;
    float a[8];
#pragma unroll
    for (int n = 0; n < 8; ++n) a[n] = ldsD2[row][n * 16 + l];
    float s2 = 0.f;
#pragma unroll
    for (int n = 0; n < 8; ++n) s2 += a[n] * a[n];
#pragma unroll
    for (int off = 1; off < 16; off <<= 1) s2 += __shfl_xor(s2, off);
    float nn = sqrtf(s2);
    float f = fminf(3.5f / (nn + EPSF), 1.0f);
    float t = fmaxf(nn * f, EPSF);
    float coef = sinhf(t) / t * f;
    float ch = coshf(t);
    if (l == 0) {
      vt[r0 + row] = ch;
      lv[r0 + row] = coef * coef * s2 - ch * ch;
    }
#pragma unroll
    for (int n = 0; n < 8; ++n) {
      float sv = coef * a[n];
      unsigned short h = f2bf(sv);
      Vhi[(size_t)(r0 + row) * 128 + n * 16 + l] = h;
      Vlo[(size_t)(r0 + row) * 128 + n * 16 + l] = f2bf(sv - bf2f(h));
      ldsT[n * 16 + l][row] = sv;
    }
  }
  __syncthreads();

  // ---- transposed store (R6 gemm_v2 pattern): thread d owns VT column d ----
  if (tid < 128) {
    int d = tid;
    unsigned int wh[8], wl[8];
#pragma unroll
    for (int i = 0; i < 8; ++i) {
      float s0 = ldsT[d][2 * i], s1 = ldsT[d][2 * i + 1];
      unsigned short h0 = f2bf(s0), h1 = f2bf(s1);
      unsigned short g0 = f2bf(s0 - bf2f(h0)), g1 = f2bf(s1 - bf2f(h1));
      wh[i] = (unsigned)h0 | ((unsigned)h1 << 16);
      wl[i] = (unsigned)g0 | ((unsigned)g1 << 16);
    }
    size_t o = (size_t)d * 2048 + r0;
    *(uint4*)(VThi + o) = make_uint4(wh[0], wh[1], wh[2], wh[3]);
    *(uint4*)(VThi + o + 8) = make_uint4(wh[4], wh[5], wh[6], wh[7]);
    *(uint4*)(VTlo + o) = make_uint4(wl[0], wl[1], wl[2], wl[3]);
    *(uint4*)(VTlo + o + 8) = make_uint4(wl[4], wl[5], wl[6], wl[7]);
  }
}

// ---------------- MFMA pair phase (R6 verbatim): 16 q x 64 j per wave, 2-way hi/lo ----------------
__launch_bounds__(256, 2)
__global__ void attn_mfma(const unsigned short* __restrict__ Qhi, const unsigned short* __restrict__ Qlo,
                          const unsigned short* __restrict__ Khi, const unsigned short* __restrict__ Klo,
                          const unsigned short* __restrict__ Vhi, const unsigned short* __restrict__ Vlo,
                          const unsigned short* __restrict__ VThi, const unsigned short* __restrict__ VTlo,
                          const float* __restrict__ qt, const float* __restrict__ lqv,
                          const float* __restrict__ kt, const float* __restrict__ vt,
                          const float* __restrict__ lv, float* __restrict__ part) {
  int tid = threadIdx.x, wv = tid >> 6, lane = tid & 63;
  int l15 = lane & 15, lh = lane >> 4;
  int qg = blockIdx.x >> 3, sp = blockIdx.x & 7;
  int q0 = qg * 16;
  int j0 = sp * 256 + wv * 64;

  __shared__ __align__(16) unsigned short ghA[4][1024];
  __shared__ __align__(16) unsigned short glA[4][1024];
  __shared__ __align__(16) float mergeO[4][16][132];
  __shared__ float mergeS[4][3][16];

  bf8_t qfh[4], qfl[4];
  {
    const unsigned short* qp = Qhi + (size_t)(q0 + l15) * 128 + lh * 8;
    const unsigned short* ql = Qlo + (size_t)(q0 + l15) * 128 + lh * 8;
#pragma unroll
    for (int ks = 0; ks < 4; ++ks) { qfh[ks] = ld8(qp + ks * 32); qfl[ks] = ld8(ql + ks * 32); }
  }
  float qtr[4], lq2[4];
#pragma unroll
  for (int r = 0; r < 4; ++r) {
    int q = q0 + lh * 4 + r;
    qtr[r] = qt[q];
    lq2[r] = 2.0f + lqv[q];
  }
  float ktj[4], vtj[4], lvj[4];
#pragma unroll
  for (int n = 0; n < 4; ++n) {
    int j = j0 + n * 16 + l15;
    ktj[n] = kt[j]; vtj[n] = vt[j]; lvj[n] = lv[j];
  }

  f32x4 sf[4], cf[4];
#pragma unroll
  for (int n = 0; n < 4; ++n) {
    f32x4 s = {0, 0, 0, 0}, c = {0, 0, 0, 0};
    size_t jrow = (size_t)(j0 + n * 16 + l15) * 128 + lh * 8;
    const unsigned short* kh = Khi + jrow;
    const unsigned short* kl = Klo + jrow;
    const unsigned short* vh = Vhi + jrow;
    const unsigned short* vl = Vlo + jrow;
#pragma unroll
    for (int ks = 0; ks < 4; ++ks) {
      bf8_t bkh = ld8(kh + ks * 32), bkl = ld8(kl + ks * 32);
      s = mfma16(qfh[ks], bkh, s);
      s = mfma16(qfh[ks], bkl, s);
      s = mfma16(qfl[ks], bkh, s);
      bf8_t bvh = ld8(vh + ks * 32), bvl = ld8(vl + ks * 32);
      c = mfma16(qfh[ks], bvh, c);
      c = mfma16(qfh[ks], bvl, c);
      c = mfma16(qfl[ks], bvh, c);
    }
    sf[n] = s; cf[n] = c;
  }

  float lsum[4] = {0, 0, 0, 0}, tcs[4] = {0, 0, 0, 0}, tts[4] = {0, 0, 0, 0};
#pragma unroll
  for (int n = 0; n < 4; ++n) {
#pragma unroll
    for (int r = 0; r < 4; ++r) {
      float sim = sf[n][r] - qtr[r] * ktj[n];
      float c = cf[n][r] - qtr[r] * vtj[n];
      float e = expf(-BETA_F * sim);
      float z = fmaxf(-c, 1.0f + EPSF);
      float dist = acoshf(z);
      float den2 = fmaxf(lvj[n] + lq2[r] * c * c, EPSF);
      float g = e * dist * rsqrtf(den2);
      lsum[r] += e;
      tcs[r] += g * c;
      tts[r] += g * vtj[n];
      unsigned short gh = f2bf(g);
      unsigned short gl = f2bf(g - bf2f(gh));
      int q_ = lh * 4 + r;
      int idx = (q_ * 64 + n * 16 + l15) ^ ((q_ & 7) << 3);
      ghA[wv][idx] = gh;
      glA[wv][idx] = gl;
    }
  }
  asm volatile("s_waitcnt lgkmcnt(0)" ::: "memory");
  __builtin_amdgcn_sched_barrier(0);

  f32x4 accO[8];
#pragma unroll
  for (int dn = 0; dn < 8; ++dn) accO[dn] = f32x4{0, 0, 0, 0};
#pragma unroll
  for (int jk = 0; jk < 2; ++jk) {
    int base = (l15 * 64 + jk * 32 + lh * 8) ^ ((l15 & 7) << 3);
    bf8_t ah = ld8(&ghA[wv][base]);
    bf8_t al = ld8(&glA[wv][base]);
#pragma unroll
    for (int dn = 0; dn < 8; ++dn) {
      size_t vrow = (size_t)(dn * 16 + l15) * 2048 + j0 + jk * 32 + lh * 8;
      bf8_t bh = ld8(VThi + vrow), bl = ld8(VTlo + vrow);
      accO[dn] = mfma16(ah, bh, accO[dn]);
      accO[dn] = mfma16(ah, bl, accO[dn]);
      accO[dn] = mfma16(al, bh, accO[dn]);
    }
  }

#pragma unroll
  for (int r = 0; r < 4; ++r) {
#pragma unroll
    for (int off = 1; off < 16; off <<= 1) {
      lsum[r] += __shfl_xor(lsum[r], off);
      tcs[r] += __shfl_xor(tcs[r], off);
      tts[r] += __shfl_xor(tts[r], off);
    }
  }

#pragma unroll
  for (int r = 0; r < 4; ++r) {
    int q_ = lh * 4 + r;
#pragma unroll
    for (int dn = 0; dn < 8; ++dn) mergeO[wv][q_][dn * 16 + l15] = accO[dn][r];
    if (l15 == 0) {
      mergeS[wv][0][q_] = lsum[r];
      mergeS[wv][1][q_] = tcs[r];
      mergeS[wv][2][q_] = tts[r];
    }
  }
  __syncthreads();

#pragma unroll
  for (int e = 0; e < 2; ++e) {
    int t = tid + e * 256;
    int q_ = t >> 5, d0 = (t & 31) * 4;
    float4 s = make_float4(0.f, 0.f, 0.f, 0.f);
#pragma unroll
    for (int w = 0; w < 4; ++w) {
      float4 v = *(const float4*)&mergeO[w][q_][d0];
      s.x += v.x; s.y += v.y; s.z += v.z; s.w += v.w;
    }
    float* P = part + ((size_t)(q0 + q_) * 8 + sp) * 132;
    *(float4*)(P + d0) = s;
  }
  if (tid < 16) {
    int q_ = tid;
    float a = 0, b = 0, cc2 = 0;
#pragma unroll
    for (int w = 0; w < 4; ++w) {
      a += mergeS[w][0][q_];
      b += mergeS[w][1][q_];
      cc2 += mergeS[w][2][q_];
    }
    float* P = part + ((size_t)(q0 + q_) * 8 + sp) * 132;
    P[128] = a; P[129] = b; P[130] = cc2;
  }
}

// ---------------- merge splits + hyperbolic epilogue (R6 verbatim) ----------------
__global__ void merge_fin(const float* __restrict__ part, const float* __restrict__ Qs,
                          const float* __restrict__ qt, float* __restrict__ out) {
  int qi = blockIdx.x;
  int lane = threadIdx.x;  // 64
  const float* P = part + (size_t)qi * 8 * 132;
  float ox = 0, oy = 0, l = 0, tc = 0, tt = 0;
#pragma unroll
  for (int s = 0; s < 8; ++s) {
    const float* p = P + s * 132;
    float2 o2 = *(const float2*)(p + 2 * lane);
    ox += o2.x; oy += o2.y;
    l += p[128]; tc += p[129]; tt += p[130];
  }
  float2 q2 = ((const float2*)(Qs + (size_t)qi * 128))[lane];
  float qtv = qt[qi];
  float invl = 1.0f / l;
  float Tmx = (ox + tc * q2.x) * invl;
  float Tmy = (oy + tc * q2.y) * invl;
  float Tmt = (tt + tc * qtv) * invl;
  float sp2 = wave_sum(Tmx * Tmx + Tmy * Tmy);
  float LT = sp2 - Tmt * Tmt;
  float un = sqrtf(fmaxf(LT, EPSF));
  float ch = coshf(un);
  float shv = sinhf(un) / un;
  float zx = ch * q2.x + shv * Tmx;
  float zy = ch * q2.y + shv * Tmy;
  float zt = ch * qtv + shv * Tmt;
  float zn2 = wave_sum(zx * zx + zy * zy);
  float nz = fmaxf(sqrtf(zn2), EPSF);
  float dist = acoshf(fmaxf(zt, 1.0f + EPSF));
  float sc = dist / nz;
  ((float2*)(out + (size_t)qi * 128))[lane] = make_float2(sc * zx, sc * zy);
}

extern "C" void kernel_launch(void* const* d_in, const int* in_sizes, int n_in,
                              void* d_out, int out_size, void* d_ws, size_t ws_size,
                              hipStream_t stream) {
  const float* queries = (const float*)d_in[0];
  const float* keys = (const float*)d_in[1];
  const float* values = (const float*)d_in[2];
  const float* WK = (const float*)d_in[3];
  const float* WV = (const float*)d_in[4];
  float* ws = (float*)d_ws;

  float* qt_ = ws + WS_QT;
  float* lq_ = ws + WS_LQ;
  float* kt_ = ws + WS_KT;
  float* vt_ = ws + WS_VTM;
  float* lv_ = ws + WS_LV;
  float* Qs = ws + WS_QS;
  unsigned short* Qhi = (unsigned short*)(ws + WS_QHI);
  unsigned short* Qlo = (unsigned short*)(ws + WS_QLO);
  unsigned short* Khi = (unsigned short*)(ws + WS_KHI);
  unsigned short* Klo = (unsigned short*)(ws + WS_KLO);
  unsigned short* Vhi = (unsigned short*)(ws + WS_VHI);
  unsigned short* Vlo = (unsigned short*)(ws + WS_VLO);
  unsigned short* VThi = (unsigned short*)(ws + WS_VTHI);
  unsigned short* VTlo = (unsigned short*)(ws + WS_VTLO);
  unsigned short* WKT0 = (unsigned short*)(ws + WS_WKT0);
  unsigned short* WKT1 = (unsigned short*)(ws + WS_WKT1);
  unsigned short* WKT2 = (unsigned short*)(ws + WS_WKT2);
  unsigned short* WVT0 = (unsigned short*)(ws + WS_WVT0);
  unsigned short* WVT1 = (unsigned short*)(ws + WS_WVT1);
  unsigned short* WVT2 = (unsigned short*)(ws + WS_WVT2);
  float* part = ws + WS_PART;
  float* out = (float*)d_out;

  prep_q<<<1024, 64, 0, stream>>>(queries, Qs, qt_, lq_, (unsigned int*)Qhi, (unsigned int*)Qlo);
  convert_w<<<320, 256, 0, stream>>>(WK, WV, WKT0, WKT1, WKT2, WVT0, WVT1, WVT2);
  prep_kv<<<256, 512, 0, stream>>>(keys, values, WKT0, WKT1, WKT2, WVT0, WVT1, WVT2,
                                   Khi, Klo, kt_, Vhi, Vlo, VThi, VTlo, vt_, lv_);
  attn_mfma<<<512, 256, 0, stream>>>(Qhi, Qlo, Khi, Klo, Vhi, Vlo, VThi, VTlo,
                                     qt_, lq_, kt_, vt_, lv_, part);
  merge_fin<<<1024, 64, 0, stream>>>(part, Qs, qt_, out);
}